// Round 1
// baseline (73.848 us; speedup 1.0000x reference)
//
#include <hip/hip_runtime.h>
#include <math.h>

#define NIMG 64
#define HW   1024
#define NCH  85
#define NCLS 80
#define CONF_TH 0.25f
#define NMS_TH  0.35f

__device__ __forceinline__ float fast_tanh(float x) {
  float e = __expf(2.0f * x);
  return 1.0f - 2.0f * __builtin_amdgcn_rcpf(e + 1.0f);
}
__device__ __forceinline__ float fast_sigmoid(float x) {
  return __builtin_amdgcn_rcpf(1.0f + __expf(-x));
}

// ---------------------------------------------------------------------------
// Decode kernel: one thread per pixel, 256 blocks x 256 threads (all 256 CUs).
// Thread t of image n walks all 85 channels at stride HW; consecutive lanes
// hit consecutive pixels -> every load is a fully-coalesced 256B wave access.
// Argmax over 80 classes split into 4 contiguous 20-class chains (independent
// compare chains, 4x shorter dep chain); ascending-chain merge with strict '>'
// reproduces exact first-occurrence argmax semantics.
// Output IS the required bboxes tensor [N, HW, 6] -> the intermediate is free.
// ---------------------------------------------------------------------------
__global__ __launch_bounds__(256) void decode_kernel(const float* __restrict__ preds,
                                                     float* __restrict__ out) {
  int gid = blockIdx.x * 256 + threadIdx.x;   // 0 .. 65535
  int n = gid >> 10;
  int t = gid & 1023;
  const float* bp = preds + (size_t)n * (NCH * HW) + t;

  float pobj = bp[0];
  float tx = bp[(size_t)1 * HW];
  float ty = bp[(size_t)2 * HW];
  float tw = bp[(size_t)3 * HW];
  float th = bp[(size_t)4 * HW];

  // 4 independent 20-class argmax chains over contiguous class blocks.
  float b0, b1, b2, b3;
  int i0, i1, i2, i3;
  b0 = bp[(size_t)(5 +  0) * HW]; i0 =  0;
  b1 = bp[(size_t)(5 + 20) * HW]; i1 = 20;
  b2 = bp[(size_t)(5 + 40) * HW]; i2 = 40;
  b3 = bp[(size_t)(5 + 60) * HW]; i3 = 60;
#pragma unroll
  for (int c = 1; c < 20; ++c) {
    float v0 = bp[(size_t)(5 +  0 + c) * HW];
    float v1 = bp[(size_t)(5 + 20 + c) * HW];
    float v2 = bp[(size_t)(5 + 40 + c) * HW];
    float v3 = bp[(size_t)(5 + 60 + c) * HW];
    if (v0 > b0) { b0 = v0; i0 =  0 + c; }
    if (v1 > b1) { b1 = v1; i1 = 20 + c; }
    if (v2 > b2) { b2 = v2; i2 = 40 + c; }
    if (v3 > b3) { b3 = v3; i3 = 60 + c; }
  }
  // Ascending-chain merge, strict '>': contiguous blocks => any index in an
  // earlier chain is smaller, so ties resolve to the first occurrence. Exact.
  float best = b0; int bc = i0;
  if (b1 > best) { best = b1; bc = i1; }
  if (b2 > best) { best = b2; bc = i2; }
  if (b3 > best) { best = b3; bc = i3; }

  float score = pobj * best;                 // bit-exact vs reference

  float gx = (float)(t & 31);
  float gy = (float)(t >> 5);
  float bcx = (fast_tanh(tx) + gx) * 0.03125f;
  float bcy = (fast_tanh(ty) + gy) * 0.03125f;
  float bw = fast_sigmoid(tw);
  float bh = fast_sigmoid(th);

  float x1 = bcx - 0.5f * bw, y1 = bcy - 0.5f * bh;
  float x2 = bcx + 0.5f * bw, y2 = bcy + 0.5f * bh;

  float2* ob = (float2*)(out + (size_t)gid * 6);
  ob[0] = make_float2(x1, y1);
  ob[1] = make_float2(x2, y2);
  ob[2] = make_float2(score, (float)bc);
}

// ---------------------------------------------------------------------------
// NMS kernel: one block per image, 1024 threads. Reads the decoded boxes back
// (1.8 MB total, L2/L3-hot). Identical phase structure and float op order to
// the previously-verified fused kernel: parallel rank + parallel suppression
// bitmasks + O(m) serial bit-scan per class.
// ---------------------------------------------------------------------------
__global__ __launch_bounds__(1024) void nms_kernel(const float* __restrict__ boxes,
                                                   float* __restrict__ keepOut) {
  int n = blockIdx.x;
  int t = threadIdx.x;

  __shared__ float sx1[HW], sy1[HW], sx2[HW], sy2[HW], sarea[HW], sscore[HW];
  __shared__ int scls[HW];
  __shared__ int bucket[HW];                 // unordered class members
  __shared__ int sorted[HW];                 // (score desc, idx asc) order
  __shared__ int srank[HW];
  __shared__ unsigned long long supp[HW];    // suppression bits vs lower ranks
  __shared__ int cnt[NCLS], offs[NCLS], start[NCLS];

  if (t < NCLS) cnt[t] = 0;

  size_t gb = (size_t)n * HW + t;
  const float2* ib = (const float2*)(boxes + gb * 6);
  float2 a01 = ib[0];
  float2 a23 = ib[1];
  float2 a45 = ib[2];
  float x1 = a01.x, y1 = a01.y, x2 = a23.x, y2 = a23.y;
  float score = a45.x;
  int bc = (int)a45.y;

  float aar = (x2 - x1) * (y2 - y1);
  sx1[t] = x1; sy1[t] = y1; sx2[t] = x2; sy2[t] = y2;
  sarea[t] = aar;
  sscore[t] = score;
  scls[t] = bc;
  bool valid = score > CONF_TH;
  keepOut[gb] = 0.0f;
  __syncthreads();

  // ---- count valid per class ----
  if (valid) atomicAdd(&cnt[bc], 1);
  __syncthreads();

  // ---- exclusive prefix sum over 80 class counts (wave-0 shfl scan) ----
  if (t < 64) {
    int c0 = (2 * t < NCLS) ? cnt[2 * t] : 0;
    int c1 = (2 * t + 1 < NCLS) ? cnt[2 * t + 1] : 0;
    int ps = c0 + c1;
    int x = ps;
#pragma unroll
    for (int d = 1; d < 64; d <<= 1) {
      int y = __shfl_up(x, d, 64);
      if (t >= d) x += y;
    }
    int excl = x - ps;
    if (2 * t < NCLS)     { start[2 * t] = excl;          offs[2 * t] = excl; }
    if (2 * t + 1 < NCLS) { start[2 * t + 1] = excl + c0; offs[2 * t + 1] = excl + c0; }
  }
  __syncthreads();

  // ---- scatter valid boxes to class buckets (order irrelevant) ----
  if (valid) {
    int p = atomicAdd(&offs[bc], 1);
    bucket[p] = t;
  }
  __syncthreads();

  // ---- parallel rank within class = exact stable-argsort position ----
  if (valid) {
    int s0 = start[bc], m = cnt[bc];
    int r = 0;
    for (int j = 0; j < m; ++j) {
      int jb = bucket[s0 + j];
      float sj = sscore[jb];
      r += (sj > score) || (sj == score && jb < t);
    }
    srank[t] = r;
    sorted[s0 + r] = t;
  }
  __syncthreads();

  // ---- parallel suppression bitmasks vs all lower-rank members ----
  if (valid) {
    int s0 = start[bc];
    int a = srank[t];
    int lim = a < 64 ? a : 64;
    unsigned long long mask = 0ull;
    for (int b = 0; b < lim; ++b) {
      int jb = sorted[s0 + b];
      float iw = fminf(x2, sx2[jb]) - fmaxf(x1, sx1[jb]);
      float ih = fminf(y2, sy2[jb]) - fmaxf(y1, sy1[jb]);
      iw = fmaxf(iw, 0.0f);
      ih = fmaxf(ih, 0.0f);
      float inter = iw * ih;
      float iou = inter / (aar + sarea[jb] - inter + 1e-9f);  // exact ref op order
      if (iou > NMS_TH) mask |= (1ull << b);
    }
    supp[s0 + a] = mask;
  }
  __syncthreads();

  // ---- serial greedy scan per class: O(m) register bit-ops ----
  if (t < NCLS) {
    int m = cnt[t], s0 = start[t];
    if (m <= 64) {
      unsigned long long kept = 0ull;
      for (int a = 0; a < m; ++a) {
        unsigned long long sa = supp[s0 + a];
        if ((sa & kept) == 0ull) {
          kept |= (1ull << a);
          keepOut[(size_t)n * HW + sorted[s0 + a]] = 1.0f;
        }
      }
    } else {
      // never expected (Poisson mean ~6/class); exact O(m^2) fallback
      for (int a = 0; a < m; ++a) {
        int ia = sorted[s0 + a];
        float ax1 = sx1[ia], ay1 = sy1[ia], ax2 = sx2[ia], ay2 = sy2[ia];
        float ar2 = sarea[ia];
        bool kp = true;
        for (int b = 0; b < a; ++b) {
          if (!bucket[s0 + b]) continue;   // bucket reused as kept-flags
          int jb = sorted[s0 + b];
          float iw = fminf(ax2, sx2[jb]) - fmaxf(ax1, sx1[jb]);
          float ih = fminf(ay2, sy2[jb]) - fmaxf(ay1, sy1[jb]);
          iw = fmaxf(iw, 0.0f);
          ih = fmaxf(ih, 0.0f);
          float inter = iw * ih;
          float iou = inter / (ar2 + sarea[jb] - inter + 1e-9f);
          if (iou > NMS_TH) { kp = false; break; }
        }
        bucket[s0 + a] = kp ? 1 : 0;
        if (kp) keepOut[(size_t)n * HW + ia] = 1.0f;
      }
    }
  }
}

extern "C" void kernel_launch(void* const* d_in, const int* in_sizes, int n_in,
                              void* d_out, int out_size, void* d_ws, size_t ws_size,
                              hipStream_t stream) {
  const float* preds = (const float*)d_in[0];
  float* out = (float*)d_out;
  float* keepOut = out + (size_t)NIMG * HW * 6;

  decode_kernel<<<NIMG * HW / 256, 256, 0, stream>>>(preds, out);
  nms_kernel<<<NIMG, HW, 0, stream>>>(out, keepOut);
}